// Round 2
// baseline (13027.174 us; speedup 1.0000x reference)
//
#include <hip/hip_runtime.h>
#include <hip/hip_bf16.h>
#include <cstdint>
#include <cstddef>

typedef float f32x4 __attribute__((ext_vector_type(4)));
typedef short s16x8 __attribute__((ext_vector_type(8)));

#define B_  256
#define T_  1024
#define D_  64
#define H_  512
#define O_  128

#define NBG   8     // batch groups (32 rows each)
#define NCG   32    // col groups (16 h-cols each)
#define MROWS 32
#define JW    16
#define NG    48    // 3 gates * JW
#define CSTR  97    // CLDS row stride in floats (avoid bank aliasing)

// ---- LDS layout (bytes) ----
#define OFF_WGH   0                 // [48][512] bf16 (W_hh rows, swizzled)   49152
#define OFF_WGI2  49152             // [48][512] bf16 (W_comb rows)           49152
#define OFF_WGIX  98304             // [48][64]  bf16 (W_ih x-part)            6144
#define OFF_WDEC  104448            // [16][512] bf16 (W_dec slice, cg<8)     16384
#define OFF_CLDS  120832            // [32][97]  f32                          12416
#define OFF_HOWN  133248            // [32][16]  f32                           2048
#define OFF_W0S   135296            // 48 f32
#define OFF_C0S   135488
#define OFF_BIHS  135680
#define OFF_BHHS  135872
#define OFF_BDECS 136064            // 16 f32
#define OFF_TSS   136128            // 32 f32
#define SMEM_BYTES 136256

// ---- workspace layout (bytes) ----
#define WS_WCOMB 0                  // [1536][512] bf16
#define WS_C0    1572864            // [1536] f32
#define WS_HSLAB 1579008            // 2 * [256][512] bf16
#define WS_CNT   2103296            // NBG * 64 uint
#define WS_TOTAL 2105344

__device__ inline f32x4 mfma16(s16x8 a, s16x8 b, f32x4 c) {
  return __builtin_amdgcn_mfma_f32_16x16x32_bf16(a, b, c, 0, 0, 0);
}

__device__ inline unsigned short f2bf(float f) {
  __hip_bfloat16 h = __float2bfloat16(f);
  unsigned short u;
  __builtin_memcpy(&u, &h, sizeof(u));
  return u;
}

__device__ inline s16x8 cvt8(const float* s) {
  union { unsigned short h[8]; s16x8 v; } p;
#pragma unroll
  for (int e = 0; e < 8; ++e) p.h[e] = f2bf(s[e]);
  return p.v;
}

// B-fragment readers (rows stored K-contiguous, 16B-block XOR swizzle by (row&7)<<4)
__device__ inline s16x8 fragK512(const char* base, int n, int kc, int kg) {
  int byteoff = n * 1024 + (((kc * 64) + (kg * 16)) ^ ((n & 7) << 4));
  return *(const s16x8*)(base + byteoff);
}
__device__ inline s16x8 fragK64(const char* base, int n, int kc, int kg) {
  int byteoff = n * 128 + (((kc * 64) + (kg * 16)) ^ ((n & 7) << 4));
  return *(const s16x8*)(base + byteoff);
}

// ---------------- W_comb = W_ih[:,1:65] @ W_dec[:64,:]  (+ c0) ----------------
__global__ void wcomb_kernel(const float* __restrict__ W_ih, const float* __restrict__ W_dec,
                             const float* __restrict__ b_ih, const float* __restrict__ b_dec,
                             unsigned short* __restrict__ Wcomb, float* __restrict__ c0) {
  __shared__ float arow[64];
  int i = blockIdx.x;
  int tid = threadIdx.x;
  if (tid < 64) arow[tid] = W_ih[(size_t)i * 65 + 1 + tid];
  __syncthreads();
  for (int j = tid; j < H_; j += 256) {
    float acc = 0.f;
#pragma unroll 8
    for (int d = 0; d < 64; ++d) acc += arow[d] * W_dec[(size_t)d * H_ + j];
    Wcomb[(size_t)i * H_ + j] = f2bf(acc);
  }
  if (tid == 0) {
    float acc = b_ih[i];
    for (int d = 0; d < 64; ++d) acc += arow[d] * b_dec[d];
    c0[i] = acc;
  }
}

// wave0-only: relaxed spin until all 32 peer slots >= target
__device__ inline void wait_peers(unsigned int* slots, int lane, unsigned target) {
  for (;;) {
    unsigned v = (lane < NCG)
        ? __hip_atomic_load(slots + lane, __ATOMIC_RELAXED, __HIP_MEMORY_SCOPE_AGENT)
        : target;
    if (__all((int)(v >= target))) break;
    __builtin_amdgcn_s_sleep(2);
  }
}

// ---------------- persistent recurrence ----------------
__global__ __launch_bounds__(256, 1) void rnn_persist(
    const float* __restrict__ xs, const float* __restrict__ ts,
    const float* __restrict__ W_ih, const float* __restrict__ W_hh,
    const float* __restrict__ b_ih, const float* __restrict__ b_hh,
    const float* __restrict__ W_dec, const float* __restrict__ b_dec,
    const int* __restrict__ cutoffp,
    const unsigned short* __restrict__ Wcomb, const float* __restrict__ c0,
    unsigned short* __restrict__ hslab, unsigned int* __restrict__ cnt,
    float* __restrict__ out) {
  extern __shared__ char sm[];
  const int wg = blockIdx.x;
  const int bg = wg & 7;         // peers of a batch group tend to land on one XCD (perf only)
  const int cg = wg >> 3;
  const int b0 = bg * MROWS;
  const int j0 = cg * JW;
  const int tid = threadIdx.x;
  const int wave = tid >> 6, lane = tid & 63;
  const int cutoff = *cutoffp;

  // ---- one-time LDS fill (weights, swizzled) ----
  for (int u = tid; u < NG * 64; u += 256) {        // W_hh rows -> bf16
    int r = u >> 6, blk = u & 63;
    int grow = (r >> 4) * H_ + j0 + (r & 15);
    s16x8 v = cvt8(W_hh + (size_t)grow * H_ + blk * 8);
    *(s16x8*)(sm + OFF_WGH + r * 1024 + ((blk * 16) ^ ((r & 7) << 4))) = v;
  }
  for (int u = tid; u < NG * 64; u += 256) {        // W_comb rows (already bf16)
    int r = u >> 6, blk = u & 63;
    int grow = (r >> 4) * H_ + j0 + (r & 15);
    s16x8 v = *(const s16x8*)(Wcomb + (size_t)grow * H_ + blk * 8);
    *(s16x8*)(sm + OFF_WGI2 + r * 1024 + ((blk * 16) ^ ((r & 7) << 4))) = v;
  }
  for (int u = tid; u < NG * 8; u += 256) {         // W_ih x-part
    int r = u >> 3, blk = u & 7;
    int grow = (r >> 4) * H_ + j0 + (r & 15);
    s16x8 v = cvt8(W_ih + (size_t)grow * 65 + 1 + blk * 8);
    *(s16x8*)(sm + OFF_WGIX + r * 128 + ((blk * 16) ^ ((r & 7) << 4))) = v;
  }
  if (cg < 8) {
    for (int u = tid; u < 16 * 64; u += 256) {      // W_dec slice
      int r = u >> 6, blk = u & 63;
      s16x8 v = cvt8(W_dec + (size_t)(cg * 16 + r) * H_ + blk * 8);
      *(s16x8*)(sm + OFF_WDEC + r * 1024 + ((blk * 16) ^ ((r & 7) << 4))) = v;
    }
    if (tid < 16) ((float*)(sm + OFF_BDECS))[tid] = b_dec[cg * 16 + tid];
  }
  if (tid < NG) {
    int grow = (tid >> 4) * H_ + j0 + (tid & 15);
    ((float*)(sm + OFF_W0S))[tid]  = W_ih[(size_t)grow * 65];
    ((float*)(sm + OFF_C0S))[tid]  = c0[grow];
    ((float*)(sm + OFF_BIHS))[tid] = b_ih[grow];
    ((float*)(sm + OFF_BHHS))[tid] = b_hh[grow];
  }
  for (int u = tid; u < MROWS * JW; u += 256) ((float*)(sm + OFF_HOWN))[u] = 0.f;
  __syncthreads();

  const int mt = wave & 1;          // M-tile (16 rows)
  const int nh = wave >> 1;         // 0: gh, 1: gi(+dec)
  const int rloc = mt * 16 + (lane & 15);
  const int kg = lane >> 4;
  float* CLDS = (float*)(sm + OFF_CLDS);
  float* HOWN = (float*)(sm + OFF_HOWN);
  float* TSS  = (float*)(sm + OFF_TSS);
  unsigned int* slots = cnt + bg * 64;
  unsigned int* hw = (unsigned int*)hslab;

  for (int t = 0; t < T_; ++t) {
    const bool use_x = (t < cutoff) || (t == 0);
    if (tid < MROWS) TSS[tid] = ts[(size_t)(b0 + tid) * T_ + t];
    if (t > 0) {
      if (wave == 0) wait_peers(slots, lane, (unsigned)t);
      __syncthreads();
      __builtin_amdgcn_fence(__ATOMIC_ACQUIRE, "agent");   // inv L1 (+L2) before reading peers' h
    }

    const unsigned short* hprev = hslab + ((t + 1) & 1) * (B_ * H_);
    f32x4 acc0{}, acc1{}, acc2{}, accd{};

    if (nh == 0) {
      if (t > 0) {
#pragma unroll
        for (int kc = 0; kc < 16; ++kc) {
          s16x8 a = *(const s16x8*)(hprev + (size_t)(b0 + rloc) * H_ + kc * 32 + kg * 8);
          acc0 = mfma16(a, fragK512(sm + OFF_WGH, 0 * 16 + (lane & 15), kc, kg), acc0);
          acc1 = mfma16(a, fragK512(sm + OFF_WGH, 1 * 16 + (lane & 15), kc, kg), acc1);
          acc2 = mfma16(a, fragK512(sm + OFF_WGH, 2 * 16 + (lane & 15), kc, kg), acc2);
        }
      }
    } else {
      const bool do_dec  = (cg < 8) && (t > 0);
      const bool do_comb = !use_x;                  // implies t >= 1
      if (do_dec || do_comb) {
#pragma unroll
        for (int kc = 0; kc < 16; ++kc) {
          s16x8 a = *(const s16x8*)(hprev + (size_t)(b0 + rloc) * H_ + kc * 32 + kg * 8);
          if (do_comb) {
            acc0 = mfma16(a, fragK512(sm + OFF_WGI2, 0 * 16 + (lane & 15), kc, kg), acc0);
            acc1 = mfma16(a, fragK512(sm + OFF_WGI2, 1 * 16 + (lane & 15), kc, kg), acc1);
            acc2 = mfma16(a, fragK512(sm + OFF_WGI2, 2 * 16 + (lane & 15), kc, kg), acc2);
          }
          if (do_dec)
            accd = mfma16(a, fragK512(sm + OFF_WDEC, (lane & 15), kc, kg), accd);
        }
      }
      if (use_x) {
#pragma unroll
        for (int kc = 0; kc < 2; ++kc) {
          const float* xsp = xs + ((size_t)(b0 + rloc) * T_ + t) * D_ + kc * 32 + kg * 8;
          s16x8 a = cvt8(xsp);
          acc0 = mfma16(a, fragK64(sm + OFF_WGIX, 0 * 16 + (lane & 15), kc, kg), acc0);
          acc1 = mfma16(a, fragK64(sm + OFF_WGIX, 1 * 16 + (lane & 15), kc, kg), acc1);
          acc2 = mfma16(a, fragK64(sm + OFF_WGIX, 2 * 16 + (lane & 15), kc, kg), acc2);
        }
      }
      if (do_dec) {                                 // decoder for step t-1 -> out
        const float bd = ((float*)(sm + OFF_BDECS))[lane & 15];
        int c = cg * 16 + (lane & 15);
#pragma unroll
        for (int reg = 0; reg < 4; ++reg) {
          int b = b0 + mt * 16 + kg * 4 + reg;
          float v = accd[reg] + bd;
          if (c >= D_) v = fmaxf(v, 0.001f);
          out[((size_t)b * T_ + (t - 1)) * O_ + c] = v;
        }
      }
    }

    // C tiles -> LDS (C layout: col = lane&15, row = kg*4 + reg)
    {
      int colb = nh * 48 + (lane & 15);
      int rowb = mt * 16 + kg * 4;
#pragma unroll
      for (int reg = 0; reg < 4; ++reg) {
        CLDS[(rowb + reg) * CSTR + colb + 0]  = acc0[reg];
        CLDS[(rowb + reg) * CSTR + colb + 16] = acc1[reg];
        CLDS[(rowb + reg) * CSTR + colb + 32] = acc2[reg];
      }
    }
    __syncthreads();

    // GRU update (512 elements; 2 per thread, packed coherent store)
    {
      const int bb = tid >> 3, jp = tid & 7;
      const float tsv = TSS[bb];
      const float* w0s  = (const float*)(sm + OFF_W0S);
      const float* c0s  = (const float*)(sm + OFF_C0S);
      const float* bihs = (const float*)(sm + OFF_BIHS);
      const float* bhhs = (const float*)(sm + OFF_BHHS);
      float hn2[2];
#pragma unroll
      for (int q = 0; q < 2; ++q) {
        int jl = jp * 2 + q;
        float gi_r = CLDS[bb * CSTR + 48 + jl]      + tsv * w0s[jl]      + (use_x ? bihs[jl]      : c0s[jl]);
        float gi_z = CLDS[bb * CSTR + 48 + 16 + jl] + tsv * w0s[16 + jl] + (use_x ? bihs[16 + jl] : c0s[16 + jl]);
        float gi_n = CLDS[bb * CSTR + 48 + 32 + jl] + tsv * w0s[32 + jl] + (use_x ? bihs[32 + jl] : c0s[32 + jl]);
        float gh_r = CLDS[bb * CSTR + jl]      + bhhs[jl];
        float gh_z = CLDS[bb * CSTR + 16 + jl] + bhhs[16 + jl];
        float gh_n = CLDS[bb * CSTR + 32 + jl] + bhhs[32 + jl];
        float r = 1.f / (1.f + __expf(-(gi_r + gh_r)));
        float z = 1.f / (1.f + __expf(-(gi_z + gh_z)));
        float n = tanhf(gi_n + r * gh_n);
        float hp = HOWN[bb * 16 + jl];
        float hn = (1.f - z) * n + z * hp;
        HOWN[bb * 16 + jl] = hn;
        hn2[q] = hn;
      }
      unsigned pk = (unsigned)f2bf(hn2[0]) | ((unsigned)f2bf(hn2[1]) << 16);
      __hip_atomic_store(hw + (size_t)(t & 1) * (B_ * H_ / 2) + ((size_t)(b0 + bb) * H_ + j0) / 2 + jp,
                         pk, __ATOMIC_RELAXED, __HIP_MEMORY_SCOPE_AGENT);
    }

    // all coherent h-stores complete (per-wave), then one flag store per WG
    asm volatile("s_waitcnt vmcnt(0)" ::: "memory");
    __syncthreads();
    if (tid == 0)
      __hip_atomic_store(slots + cg, (unsigned)(t + 1), __ATOMIC_RELAXED, __HIP_MEMORY_SCOPE_AGENT);
  }

  // decoder for the final step t = T-1
  if (cg < 8) {
    if (wave == 0) wait_peers(slots, lane, (unsigned)T_);
    __syncthreads();
    __builtin_amdgcn_fence(__ATOMIC_ACQUIRE, "agent");
    if (nh == 1) {
      const unsigned short* hprev = hslab + ((T_ - 1) & 1) * (B_ * H_);
      f32x4 accd{};
#pragma unroll
      for (int kc = 0; kc < 16; ++kc) {
        s16x8 a = *(const s16x8*)(hprev + (size_t)(b0 + rloc) * H_ + kc * 32 + kg * 8);
        accd = mfma16(a, fragK512(sm + OFF_WDEC, (lane & 15), kc, kg), accd);
      }
      const float bd = ((float*)(sm + OFF_BDECS))[lane & 15];
      int c = cg * 16 + (lane & 15);
#pragma unroll
      for (int reg = 0; reg < 4; ++reg) {
        int b = b0 + mt * 16 + kg * 4 + reg;
        float v = accd[reg] + bd;
        if (c >= D_) v = fmaxf(v, 0.001f);
        out[((size_t)b * T_ + (T_ - 1)) * O_ + c] = v;
      }
    }
  }
}

extern "C" void kernel_launch(void* const* d_in, const int* in_sizes, int n_in,
                              void* d_out, int out_size, void* d_ws, size_t ws_size,
                              hipStream_t stream) {
  const float* xs    = (const float*)d_in[0];
  const float* ts    = (const float*)d_in[1];
  const float* W_ih  = (const float*)d_in[2];
  const float* W_hh  = (const float*)d_in[3];
  const float* b_ih  = (const float*)d_in[4];
  const float* b_hh  = (const float*)d_in[5];
  const float* W_dec = (const float*)d_in[6];
  const float* b_dec = (const float*)d_in[7];
  const int* cutoff  = (const int*)d_in[8];
  float* out = (float*)d_out;

  char* ws = (char*)d_ws;
  unsigned short* Wcomb = (unsigned short*)(ws + WS_WCOMB);
  float* c0             = (float*)(ws + WS_C0);
  unsigned short* hslab = (unsigned short*)(ws + WS_HSLAB);
  unsigned int* cnt     = (unsigned int*)(ws + WS_CNT);

  hipMemsetAsync(cnt, 0, NBG * 64 * sizeof(unsigned int), stream);
  wcomb_kernel<<<1536, 256, 0, stream>>>(W_ih, W_dec, b_ih, b_dec, Wcomb, c0);
  hipFuncSetAttribute(reinterpret_cast<const void*>(rnn_persist),
                      hipFuncAttributeMaxDynamicSharedMemorySize, SMEM_BYTES);
  rnn_persist<<<256, 256, SMEM_BYTES, stream>>>(xs, ts, W_ih, W_hh, b_ih, b_hh,
                                                W_dec, b_dec, cutoff, Wcomb, c0,
                                                hslab, cnt, out);
}

// Round 5
// 9485.587 us; speedup vs baseline: 1.3734x; 1.3734x over previous
//
#include <hip/hip_runtime.h>
#include <hip/hip_bf16.h>
#include <cstdint>
#include <cstddef>

typedef float f32x4 __attribute__((ext_vector_type(4)));
typedef short s16x8 __attribute__((ext_vector_type(8)));

#define B_  256
#define T_  1024
#define D_  64
#define H_  512
#define O_  128
#define JW  16
#define NG  48

// ---- LDS layout (bytes) ----
#define OFF_WGH   0                 // [48][512] bf16 W_hh rows (swizzled)
#define OFF_WGI2  49152             // [48][512] bf16 W_comb rows
#define OFF_WGIX  98304             // [48][64]  bf16 W_ih x-part
#define OFF_WDEC  104448            // [16][512] bf16 W_dec slice (cg<8)
#define OFF_W0S   120832
#define OFF_C0S   121024
#define OFF_BIHS  121216
#define OFF_BHHS  121408
#define OFF_BDECS 121600
#define OFF_MBX   121664            // 3 volatile ints: mbx, w1d, d3d
#define SMEM_BYTES 121728           // >80KB -> 1 WG/CU (co-residency guaranteed)

// ---- workspace layout (bytes) ----
#define WS_WCOMB 0                  // [1536][512] bf16
#define WS_C0    1572864            // [1536] f32
#define WS_HSLAB 1579008            // 2 * [256][512] bf16
#define WS_CFLG  2103296            // 256 uint: cflag[bg*32+cg]
#define WS_DFLG  2104320            // 64  uint: dflag[bg*8+cg], cg<8
#define WS_CTLSZ 1280               // memset span [WS_CFLG, WS_CFLG+1280)

__device__ inline f32x4 mfma16(s16x8 a, s16x8 b, f32x4 c) {
  return __builtin_amdgcn_mfma_f32_16x16x32_bf16(a, b, c, 0, 0, 0);
}

__device__ inline unsigned short f2bf(float f) {
  __hip_bfloat16 h = __float2bfloat16(f);
  unsigned short u;
  __builtin_memcpy(&u, &h, sizeof(u));
  return u;
}

__device__ inline s16x8 cvt8(const float* s) {
  union { unsigned short h[8]; s16x8 v; } p;
#pragma unroll
  for (int e = 0; e < 8; ++e) p.h[e] = f2bf(s[e]);
  return p.v;
}

// B-fragment readers (rows K-contiguous, 16B-block XOR swizzle by (row&7)<<4)
__device__ inline s16x8 fragK512(const char* base, int n, int kc, int kg) {
  int byteoff = n * 1024 + (((kc * 64) + (kg * 16)) ^ ((n & 7) << 4));
  return *(const s16x8*)(base + byteoff);
}
__device__ inline s16x8 fragK64(const char* base, int n, int kc, int kg) {
  int byteoff = n * 128 + (((kc * 64) + (kg * 16)) ^ ((n & 7) << 4));
  return *(const s16x8*)(base + byteoff);
}

// wave-uniform: lanes<32 poll cflags for tc, lanes 32..39 poll dflags for td
__device__ inline void poll_step(const unsigned* cf, const unsigned* df, int lane,
                                 unsigned tc, unsigned td, int& budget) {
  const unsigned* a;
  unsigned tgt;
  if (lane < 32)      { a = cf + lane;        tgt = tc; }
  else if (lane < 40) { a = df + (lane - 32); tgt = td; }
  else                { a = nullptr;          tgt = 0;  }
  for (;;) {
    unsigned v = a ? __hip_atomic_load(a, __ATOMIC_RELAXED, __HIP_MEMORY_SCOPE_AGENT)
                   : 0u;
    if (__all((int)(v >= tgt))) break;
    if (--budget <= 0) break;
    __builtin_amdgcn_s_sleep(1);
  }
  asm volatile("" ::: "memory");
}

__device__ inline void lds_wait(volatile int* p, int t) {
  while (*p < t) { __builtin_amdgcn_s_sleep(1); }
  asm volatile("" ::: "memory");
}

// ---------------- W_comb = W_ih[:,1:65] @ W_dec[:64,:]  (+ c0) ----------------
__global__ void wcomb_kernel(const float* __restrict__ W_ih, const float* __restrict__ W_dec,
                             const float* __restrict__ b_ih, const float* __restrict__ b_dec,
                             unsigned short* __restrict__ Wcomb, float* __restrict__ c0) {
  __shared__ float arow[64];
  int i = blockIdx.x;
  int tid = threadIdx.x;
  if (tid < 64) arow[tid] = W_ih[(size_t)i * 65 + 1 + tid];
  __syncthreads();
  for (int j = tid; j < H_; j += 256) {
    float acc = 0.f;
#pragma unroll 8
    for (int d = 0; d < 64; ++d) acc += arow[d] * W_dec[(size_t)d * H_ + j];
    Wcomb[(size_t)i * H_ + j] = f2bf(acc);
  }
  if (tid == 0) {
    float acc = b_ih[i];
    for (int d = 0; d < 64; ++d) acc += arow[d] * b_dec[d];
    c0[i] = acc;
  }
}

// ---------------- persistent recurrence ----------------
__global__ __launch_bounds__(256, 1) void rnn_persist(
    const float* __restrict__ xs, const float* __restrict__ ts,
    const float* __restrict__ W_ih, const float* __restrict__ W_hh,
    const float* __restrict__ b_ih, const float* __restrict__ b_hh,
    const float* __restrict__ W_dec, const float* __restrict__ b_dec,
    const int* __restrict__ cutoffp,
    const unsigned short* __restrict__ Wcomb, const float* __restrict__ c0,
    unsigned short* __restrict__ hslab, unsigned* __restrict__ cflags,
    unsigned* __restrict__ dflags, float* __restrict__ out) {
  extern __shared__ char sm[];
  const int tid = threadIdx.x;
  const int wave = tid >> 6, lane = tid & 63;
  const int jl = lane & 15, kg = lane >> 4;
  const int cutoff = *cutoffp;

  const int bg = blockIdx.x & 7;
  const int cg = blockIdx.x >> 3;
  const int b0 = bg * 32;
  const int j0 = cg * JW;

  // ---- one-time LDS fill (weights, swizzled; R2-proven) ----
  for (int u = tid; u < NG * 64; u += 256) {
    int r = u >> 6, blk = u & 63;
    int grow = (r >> 4) * H_ + j0 + (r & 15);
    s16x8 v = cvt8(W_hh + (size_t)grow * H_ + blk * 8);
    *(s16x8*)(sm + OFF_WGH + r * 1024 + ((blk * 16) ^ ((r & 7) << 4))) = v;
  }
  for (int u = tid; u < NG * 64; u += 256) {
    int r = u >> 6, blk = u & 63;
    int grow = (r >> 4) * H_ + j0 + (r & 15);
    s16x8 v = *(const s16x8*)(Wcomb + (size_t)grow * H_ + blk * 8);
    *(s16x8*)(sm + OFF_WGI2 + r * 1024 + ((blk * 16) ^ ((r & 7) << 4))) = v;
  }
  for (int u = tid; u < NG * 8; u += 256) {
    int r = u >> 3, blk = u & 7;
    int grow = (r >> 4) * H_ + j0 + (r & 15);
    s16x8 v = cvt8(W_ih + (size_t)grow * 65 + 1 + blk * 8);
    *(s16x8*)(sm + OFF_WGIX + r * 128 + ((blk * 16) ^ ((r & 7) << 4))) = v;
  }
  if (cg < 8) {
    for (int u = tid; u < 16 * 64; u += 256) {
      int r = u >> 6, blk = u & 63;
      s16x8 v = cvt8(W_dec + (size_t)(cg * 16 + r) * H_ + blk * 8);
      *(s16x8*)(sm + OFF_WDEC + r * 1024 + ((blk * 16) ^ ((r & 7) << 4))) = v;
    }
    if (tid < 16) ((float*)(sm + OFF_BDECS))[tid] = b_dec[cg * 16 + tid];
  }
  if (tid < NG) {
    int grow = (tid >> 4) * H_ + j0 + (tid & 15);
    ((float*)(sm + OFF_W0S))[tid]  = W_ih[(size_t)grow * 65];
    ((float*)(sm + OFF_C0S))[tid]  = c0[grow];
    ((float*)(sm + OFF_BIHS))[tid] = b_ih[grow];
    ((float*)(sm + OFF_BHHS))[tid] = b_hh[grow];
  }
  if (tid == 0) {
    ((volatile int*)(sm + OFF_MBX))[0] = 0;   // mbx
    ((volatile int*)(sm + OFF_MBX))[1] = 0;   // w1d
    ((volatile int*)(sm + OFF_MBX))[2] = 0;   // d3d
  }
  __syncthreads();

  const int mt = wave & 1;
  const int rowg = b0 + mt * 16 + jl;          // A-frag row
  const size_t arow = (size_t)rowg * H_;
  const int hrow = b0 + mt * 16 + kg * 4;      // C-tile row base
  const unsigned* cf = cflags + bg * 32;
  const unsigned* df = dflags + bg * 8;
  unsigned* myflag  = cflags + bg * 32 + cg;
  unsigned* mydflag = dflags + bg * 8 + cg;    // cg<8 only
  volatile int* mbx = (volatile int*)(sm + OFF_MBX);
  volatile int* w1d = mbx + 1;
  volatile int* d3d = mbx + 2;
  int budget = 10000000;

  if (wave < 2) {
    // ============ compute wave (mt=0/1): gh + gi + GRU in-register ============
    const float* W0S  = (const float*)(sm + OFF_W0S);
    const float* C0S  = (const float*)(sm + OFF_C0S);
    const float* BIHS = (const float*)(sm + OFF_BIHS);
    const float* BHHS = (const float*)(sm + OFF_BHHS);
    const float w0r = W0S[jl],  w0z = W0S[16 + jl],  w0n = W0S[32 + jl];
    const float bir = BIHS[jl], biz = BIHS[16 + jl], bin_ = BIHS[32 + jl];
    const float c0r = C0S[jl],  c0z = C0S[16 + jl],  c0n = C0S[32 + jl];
    const float bhr = BHHS[jl], bhz = BHHS[16 + jl], bhn = BHHS[32 + jl];

    s16x8 whhf[3][16];
#pragma unroll
    for (int g = 0; g < 3; ++g)
#pragma unroll
      for (int kc = 0; kc < 16; ++kc)
        whhf[g][kc] = fragK512(sm + OFF_WGH, g * 16 + jl, kc, kg);

    float hp[4] = {0.f, 0.f, 0.f, 0.f};

    for (int t = 0; t < T_; ++t) {
      const bool use_x = (t < cutoff) || (t == 0);
      unsigned short* hcur = hslab + (size_t)(t & 1) * (B_ * H_);
      const unsigned short* hpv = hslab + (size_t)((t + 1) & 1) * (B_ * H_);

      // prefetch ts/xs into registers BEFORE the gate (values immune to fences)
      float tsv[4];
#pragma unroll
      for (int reg = 0; reg < 4; ++reg) tsv[reg] = ts[(size_t)(hrow + reg) * T_ + t];
      s16x8 ax0{}, ax1{};
      if (use_x) {
        ax0 = cvt8(xs + ((size_t)rowg * T_ + t) * D_ + kg * 8);
        ax1 = cvt8(xs + ((size_t)rowg * T_ + t) * D_ + 32 + kg * 8);
      }

      f32x4 g0{}, g1{}, g2{}, i0{}, i1{}, i2{};

      if (t > 0) {
        if (wave == 0) {
          poll_step(cf, df, lane, (unsigned)t, (unsigned)(t - 1), budget);
          __builtin_amdgcn_fence(__ATOMIC_ACQUIRE, "agent");
          asm volatile("s_waitcnt vmcnt(0) lgkmcnt(0)" ::: "memory");
          *mbx = t;
        } else {
          lds_wait(mbx, t);
          __builtin_amdgcn_fence(__ATOMIC_ACQUIRE, "agent");
        }
        s16x8 a[16];
#pragma unroll
        for (int kc = 0; kc < 16; ++kc)
          a[kc] = *(const s16x8*)(hpv + arow + kc * 32 + kg * 8);
        if (!use_x) {
#pragma unroll
          for (int kc = 0; kc < 16; ++kc) {
            g0 = mfma16(a[kc], whhf[0][kc], g0);
            g1 = mfma16(a[kc], whhf[1][kc], g1);
            g2 = mfma16(a[kc], whhf[2][kc], g2);
            i0 = mfma16(a[kc], fragK512(sm + OFF_WGI2, jl,      kc, kg), i0);
            i1 = mfma16(a[kc], fragK512(sm + OFF_WGI2, 16 + jl, kc, kg), i1);
            i2 = mfma16(a[kc], fragK512(sm + OFF_WGI2, 32 + jl, kc, kg), i2);
          }
        } else {
#pragma unroll
          for (int kc = 0; kc < 16; ++kc) {
            g0 = mfma16(a[kc], whhf[0][kc], g0);
            g1 = mfma16(a[kc], whhf[1][kc], g1);
            g2 = mfma16(a[kc], whhf[2][kc], g2);
          }
        }
      }
      if (use_x) {
        i0 = mfma16(ax0, fragK64(sm + OFF_WGIX, jl,      0, kg), i0);
        i1 = mfma16(ax0, fragK64(sm + OFF_WGIX, 16 + jl, 0, kg), i1);
        i2 = mfma16(ax0, fragK64(sm + OFF_WGIX, 32 + jl, 0, kg), i2);
        i0 = mfma16(ax1, fragK64(sm + OFF_WGIX, jl,      1, kg), i0);
        i1 = mfma16(ax1, fragK64(sm + OFF_WGIX, 16 + jl, 1, kg), i1);
        i2 = mfma16(ax1, fragK64(sm + OFF_WGIX, 32 + jl, 1, kg), i2);
      }

      // GRU in-register (all 6 gate tiles share (lane,reg) layout)
#pragma unroll
      for (int reg = 0; reg < 4; ++reg) {
        const float xr = i0[reg] + tsv[reg] * w0r + (use_x ? bir : c0r) + g0[reg] + bhr;
        const float xz = i1[reg] + tsv[reg] * w0z + (use_x ? biz : c0z) + g1[reg] + bhz;
        const float an = i2[reg] + tsv[reg] * w0n + (use_x ? bin_ : c0n);
        const float gn = g2[reg] + bhn;
        const float r = 1.f / (1.f + __expf(-xr));
        const float z = 1.f / (1.f + __expf(-xz));
        const float n = tanhf(an + r * gn);
        const float hn = (1.f - z) * n + z * hp[reg];
        hp[reg] = hn;
        __hip_atomic_store(hcur + (size_t)(hrow + reg) * H_ + j0 + jl, f2bf(hn),
                           __ATOMIC_RELAXED, __HIP_MEMORY_SCOPE_AGENT);
      }
      asm volatile("s_waitcnt vmcnt(0)" ::: "memory");   // h at coherence point
      if (wave == 1) {
        if (lane == 0) *w1d = t + 1;
      } else if (lane == 0) {
        while (*w1d < t + 1) { __builtin_amdgcn_s_sleep(1); }
        __hip_atomic_store(myflag, (unsigned)(t + 1),
                           __ATOMIC_RELAXED, __HIP_MEMORY_SCOPE_AGENT);
      }
    }
    return;
  }

  // ============ decoder waves (2,3); only cg<8 participate ============
  if (cg >= 8) return;
  {
    s16x8 wd[16];
#pragma unroll
    for (int kc = 0; kc < 16; ++kc)
      wd[kc] = fragK512(sm + OFF_WDEC, jl, kc, kg);
    const float bd = ((const float*)(sm + OFF_BDECS))[jl];
    const int c = cg * 16 + jl;

    for (int v = 1; v < T_; ++v) {
      lds_wait(mbx, v);                                  // wave0 certified cflags>=v
      __builtin_amdgcn_fence(__ATOMIC_ACQUIRE, "agent");
      const unsigned short* hpv = hslab + (size_t)((v - 1) & 1) * (B_ * H_);
      s16x8 a[16];
#pragma unroll
      for (int kc = 0; kc < 16; ++kc)
        a[kc] = *(const s16x8*)(hpv + arow + kc * 32 + kg * 8);
      asm volatile("s_waitcnt vmcnt(0)" ::: "memory");   // reads done -> slab reusable
      if (wave == 3) {
        if (lane == 0) *d3d = v;
      } else if (lane == 0) {
        while (*d3d < v) { __builtin_amdgcn_s_sleep(1); }
        __hip_atomic_store(mydflag, (unsigned)v,
                           __ATOMIC_RELAXED, __HIP_MEMORY_SCOPE_AGENT);
      }
      f32x4 d{};
#pragma unroll
      for (int kc = 0; kc < 16; ++kc)
        d = mfma16(a[kc], wd[kc], d);
#pragma unroll
      for (int reg = 0; reg < 4; ++reg) {
        float vv = d[reg] + bd;
        if (c >= D_) vv = fmaxf(vv, 0.001f);
        out[((size_t)(hrow + reg) * T_ + (v - 1)) * O_ + c] = vv;
      }
    }

    // final step: h(T-1)
    if (wave == 2) {
      int bud2 = 10000000;
      poll_step(cf, cf, lane, (unsigned)T_, 0u, bud2);   // cflags only
      __builtin_amdgcn_fence(__ATOMIC_ACQUIRE, "agent");
      asm volatile("s_waitcnt vmcnt(0) lgkmcnt(0)" ::: "memory");
      if (lane == 0) *mbx = T_;
    } else {
      lds_wait(mbx, T_);
      __builtin_amdgcn_fence(__ATOMIC_ACQUIRE, "agent");
    }
    const unsigned short* hpv = hslab + (size_t)((T_ - 1) & 1) * (B_ * H_);
    s16x8 a[16];
#pragma unroll
    for (int kc = 0; kc < 16; ++kc)
      a[kc] = *(const s16x8*)(hpv + arow + kc * 32 + kg * 8);
    f32x4 d{};
#pragma unroll
    for (int kc = 0; kc < 16; ++kc)
      d = mfma16(a[kc], wd[kc], d);
#pragma unroll
    for (int reg = 0; reg < 4; ++reg) {
      float vv = d[reg] + bd;
      if (c >= D_) vv = fmaxf(vv, 0.001f);
      out[((size_t)(hrow + reg) * T_ + (T_ - 1)) * O_ + c] = vv;
    }
  }
}

extern "C" void kernel_launch(void* const* d_in, const int* in_sizes, int n_in,
                              void* d_out, int out_size, void* d_ws, size_t ws_size,
                              hipStream_t stream) {
  const float* xs    = (const float*)d_in[0];
  const float* ts    = (const float*)d_in[1];
  const float* W_ih  = (const float*)d_in[2];
  const float* W_hh  = (const float*)d_in[3];
  const float* b_ih  = (const float*)d_in[4];
  const float* b_hh  = (const float*)d_in[5];
  const float* W_dec = (const float*)d_in[6];
  const float* b_dec = (const float*)d_in[7];
  const int* cutoff  = (const int*)d_in[8];
  float* out = (float*)d_out;

  char* ws = (char*)d_ws;
  unsigned short* Wcomb = (unsigned short*)(ws + WS_WCOMB);
  float* c0             = (float*)(ws + WS_C0);
  unsigned short* hslab = (unsigned short*)(ws + WS_HSLAB);
  unsigned* cflags      = (unsigned*)(ws + WS_CFLG);
  unsigned* dflags      = (unsigned*)(ws + WS_DFLG);

  hipMemsetAsync(ws + WS_CFLG, 0, WS_CTLSZ, stream);
  wcomb_kernel<<<1536, 256, 0, stream>>>(W_ih, W_dec, b_ih, b_dec, Wcomb, c0);
  hipFuncSetAttribute(reinterpret_cast<const void*>(rnn_persist),
                      hipFuncAttributeMaxDynamicSharedMemorySize, SMEM_BYTES);
  rnn_persist<<<256, 256, SMEM_BYTES, stream>>>(xs, ts, W_ih, W_hh, b_ih, b_hh,
                                                W_dec, b_dec, cutoff, Wcomb, c0,
                                                hslab, cflags, dflags, out);
}

// Round 7
// 7030.595 us; speedup vs baseline: 1.8529x; 1.3492x over previous
//
#include <hip/hip_runtime.h>
#include <hip/hip_bf16.h>
#include <cstdint>
#include <cstddef>

typedef float f32x4 __attribute__((ext_vector_type(4)));
typedef short s16x8 __attribute__((ext_vector_type(8)));

#define B_  256
#define T_  1024
#define D_  64
#define H_  512
#define O_  128
#define JW  16
#define NG  48

// ---- LDS layout (bytes) ----
#define OFF_WGH   0                 // [48][512] bf16 W_hh rows (swizzled)
#define OFF_WGI2  49152             // [48][512] bf16 W_comb rows
#define OFF_WGIX  98304             // [48][64]  bf16 W_ih x-part
#define OFF_WDEC  104448            // [16][512] bf16 W_dec slice (cg<8)
#define OFF_W0S   120832
#define OFF_C0S   121024
#define OFF_BIHS  121216
#define OFF_BHHS  121408
#define OFF_BDECS 121600
#define OFF_MBX   121664            // 3 volatile ints: mbx, w1d, d3d
#define OFF_SCR   121728            // 2 waves * 16x16 u16 transpose scratch (1024B)
#define SMEM_BYTES 122752           // >80KB -> 1 WG/CU (co-residency guaranteed)

// ---- workspace layout (bytes) ----
#define WS_WCOMB 0                  // [1536][512] bf16
#define WS_C0    1572864            // [1536] f32
#define WS_HSLAB 1579008            // 2 * [256][512] bf16
#define WS_CFLG  2103296            // 256 uint
#define WS_DFLG  2104320            // 64 uint
#define WS_CTLSZ 1280               // memset [WS_CFLG, WS_CFLG+1280)

__device__ inline f32x4 mfma16(s16x8 a, s16x8 b, f32x4 c) {
  return __builtin_amdgcn_mfma_f32_16x16x32_bf16(a, b, c, 0, 0, 0);
}

__device__ inline unsigned short f2bf(float f) {
  __hip_bfloat16 h = __float2bfloat16(f);
  unsigned short u;
  __builtin_memcpy(&u, &h, sizeof(u));
  return u;
}

__device__ inline s16x8 cvt8(const float* s) {
  union { unsigned short h[8]; s16x8 v; } p;
#pragma unroll
  for (int e = 0; e < 8; ++e) p.h[e] = f2bf(s[e]);
  return p.v;
}

// B-fragment readers (rows K-contiguous, 16B-block XOR swizzle by (row&7)<<4)
__device__ inline s16x8 fragK512(const char* base, int n, int kc, int kg) {
  int byteoff = n * 1024 + (((kc * 64) + (kg * 16)) ^ ((n & 7) << 4));
  return *(const s16x8*)(base + byteoff);
}
__device__ inline s16x8 fragK64(const char* base, int n, int kc, int kg) {
  int byteoff = n * 128 + (((kc * 64) + (kg * 16)) ^ ((n & 7) << 4));
  return *(const s16x8*)(base + byteoff);
}

// coherent-point (agent) load of one 16B MFMA A-fragment as 2x u64 atomic loads
__device__ inline s16x8 ld_frag_agent(const unsigned long long* hq, int idx) {
  union { unsigned long long q[2]; s16x8 v; } u;
  u.q[0] = __hip_atomic_load(hq + idx,     __ATOMIC_RELAXED, __HIP_MEMORY_SCOPE_AGENT);
  u.q[1] = __hip_atomic_load(hq + idx + 1, __ATOMIC_RELAXED, __HIP_MEMORY_SCOPE_AGENT);
  return u.v;
}

// lanes<32 poll cflags for tc, lanes 32..39 poll dflags for td (R5-proven)
__device__ inline void poll_step(const unsigned* cf, const unsigned* df, int lane,
                                 unsigned tc, unsigned td, int& budget) {
  const unsigned* a;
  unsigned tgt;
  if (lane < 32)      { a = cf + lane;        tgt = tc; }
  else if (lane < 40) { a = df + (lane - 32); tgt = td; }
  else                { a = nullptr;          tgt = 0;  }
  for (;;) {
    unsigned v = a ? __hip_atomic_load(a, __ATOMIC_RELAXED, __HIP_MEMORY_SCOPE_AGENT)
                   : 0u;
    if (__all((int)(v >= tgt))) break;
    if (--budget <= 0) break;
    __builtin_amdgcn_s_sleep(1);
  }
  asm volatile("" ::: "memory");
}

__device__ inline void lds_wait(volatile int* p, int t) {
  while (*p < t) { __builtin_amdgcn_s_sleep(1); }
  asm volatile("" ::: "memory");
}

// ---------------- W_comb = W_ih[:,1:65] @ W_dec[:64,:]  (+ c0) ----------------
__global__ void wcomb_kernel(const float* __restrict__ W_ih, const float* __restrict__ W_dec,
                             const float* __restrict__ b_ih, const float* __restrict__ b_dec,
                             unsigned short* __restrict__ Wcomb, float* __restrict__ c0) {
  __shared__ float arow[64];
  int i = blockIdx.x;
  int tid = threadIdx.x;
  if (tid < 64) arow[tid] = W_ih[(size_t)i * 65 + 1 + tid];
  __syncthreads();
  for (int j = tid; j < H_; j += 256) {
    float acc = 0.f;
#pragma unroll 8
    for (int d = 0; d < 64; ++d) acc += arow[d] * W_dec[(size_t)d * H_ + j];
    Wcomb[(size_t)i * H_ + j] = f2bf(acc);
  }
  if (tid == 0) {
    float acc = b_ih[i];
    for (int d = 0; d < 64; ++d) acc += arow[d] * b_dec[d];
    c0[i] = acc;
  }
}

// ---------------- persistent recurrence ----------------
__global__ __launch_bounds__(256, 1) void rnn_persist(
    const float* __restrict__ xs, const float* __restrict__ ts,
    const float* __restrict__ W_ih, const float* __restrict__ W_hh,
    const float* __restrict__ b_ih, const float* __restrict__ b_hh,
    const float* __restrict__ W_dec, const float* __restrict__ b_dec,
    const int* __restrict__ cutoffp,
    const unsigned short* __restrict__ Wcomb, const float* __restrict__ c0,
    unsigned short* __restrict__ hslab, unsigned* __restrict__ cflags,
    unsigned* __restrict__ dflags, float* __restrict__ out) {
  extern __shared__ char sm[];
  const int tid = threadIdx.x;
  const int wave = tid >> 6, lane = tid & 63;
  const int jl = lane & 15, kg = lane >> 4;
  const int cutoff = *cutoffp;

  const int bg = blockIdx.x & 7;
  const int cg = blockIdx.x >> 3;
  const int b0 = bg * 32;
  const int j0 = cg * JW;

  // ---- one-time LDS fill (weights, swizzled; R2-proven) ----
  for (int u = tid; u < NG * 64; u += 256) {
    int r = u >> 6, blk = u & 63;
    int grow = (r >> 4) * H_ + j0 + (r & 15);
    s16x8 v = cvt8(W_hh + (size_t)grow * H_ + blk * 8);
    *(s16x8*)(sm + OFF_WGH + r * 1024 + ((blk * 16) ^ ((r & 7) << 4))) = v;
  }
  for (int u = tid; u < NG * 64; u += 256) {
    int r = u >> 6, blk = u & 63;
    int grow = (r >> 4) * H_ + j0 + (r & 15);
    s16x8 v = *(const s16x8*)(Wcomb + (size_t)grow * H_ + blk * 8);
    *(s16x8*)(sm + OFF_WGI2 + r * 1024 + ((blk * 16) ^ ((r & 7) << 4))) = v;
  }
  for (int u = tid; u < NG * 8; u += 256) {
    int r = u >> 3, blk = u & 7;
    int grow = (r >> 4) * H_ + j0 + (r & 15);
    s16x8 v = cvt8(W_ih + (size_t)grow * 65 + 1 + blk * 8);
    *(s16x8*)(sm + OFF_WGIX + r * 128 + ((blk * 16) ^ ((r & 7) << 4))) = v;
  }
  if (cg < 8) {
    for (int u = tid; u < 16 * 64; u += 256) {
      int r = u >> 6, blk = u & 63;
      s16x8 v = cvt8(W_dec + (size_t)(cg * 16 + r) * H_ + blk * 8);
      *(s16x8*)(sm + OFF_WDEC + r * 1024 + ((blk * 16) ^ ((r & 7) << 4))) = v;
    }
    if (tid < 16) ((float*)(sm + OFF_BDECS))[tid] = b_dec[cg * 16 + tid];
  }
  if (tid < NG) {
    int grow = (tid >> 4) * H_ + j0 + (tid & 15);
    ((float*)(sm + OFF_W0S))[tid]  = W_ih[(size_t)grow * 65];
    ((float*)(sm + OFF_C0S))[tid]  = c0[grow];
    ((float*)(sm + OFF_BIHS))[tid] = b_ih[grow];
    ((float*)(sm + OFF_BHHS))[tid] = b_hh[grow];
  }
  if (tid == 0) {
    ((volatile int*)(sm + OFF_MBX))[0] = 0;   // mbx
    ((volatile int*)(sm + OFF_MBX))[1] = 0;   // w1d
    ((volatile int*)(sm + OFF_MBX))[2] = 0;   // d3d
  }
  __syncthreads();

  const int mt = wave & 1;
  const int rowg = b0 + mt * 16 + jl;          // A-frag row
  const size_t arow = (size_t)rowg * H_;
  const int hrow = b0 + mt * 16 + kg * 4;      // C-tile row base
  const unsigned* cf = cflags + bg * 32;
  const unsigned* df = dflags + bg * 8;
  unsigned* myflag  = cflags + bg * 32 + cg;
  unsigned* mydflag = dflags + bg * 8 + cg;    // cg<8 only
  volatile int* mbx = (volatile int*)(sm + OFF_MBX);
  volatile int* w1d = mbx + 1;
  volatile int* d3d = mbx + 2;
  int budget = 10000000;

  if (wave < 2) {
    // ============ compute wave (mt=0/1): gh + gi + GRU in-register ============
    const float* W0S  = (const float*)(sm + OFF_W0S);
    const float* C0S  = (const float*)(sm + OFF_C0S);
    const float* BIHS = (const float*)(sm + OFF_BIHS);
    const float* BHHS = (const float*)(sm + OFF_BHHS);
    const float w0r = W0S[jl],  w0z = W0S[16 + jl],  w0n = W0S[32 + jl];
    const float bir = BIHS[jl], biz = BIHS[16 + jl], bin_ = BIHS[32 + jl];
    const float c0r = C0S[jl],  c0z = C0S[16 + jl],  c0n = C0S[32 + jl];
    const float bhr = BHHS[jl], bhz = BHHS[16 + jl], bhn = BHHS[32 + jl];
    unsigned short* scr = (unsigned short*)(sm + OFF_SCR) + mt * 256;

    s16x8 whhf[3][16];
#pragma unroll
    for (int g = 0; g < 3; ++g)
#pragma unroll
      for (int kc = 0; kc < 16; ++kc)
        whhf[g][kc] = fragK512(sm + OFF_WGH, g * 16 + jl, kc, kg);

    float hp[4] = {0.f, 0.f, 0.f, 0.f};

    for (int t = 0; t < T_; ++t) {
      const bool use_x = (t < cutoff) || (t == 0);
      unsigned short* hcur = hslab + (size_t)(t & 1) * (B_ * H_);
      const unsigned short* hpv = hslab + (size_t)((t + 1) & 1) * (B_ * H_);

      // prefetch ts/xs (plain loads; stay L2-resident — no fences in this kernel)
      float tsv[4];
#pragma unroll
      for (int reg = 0; reg < 4; ++reg) tsv[reg] = ts[(size_t)(hrow + reg) * T_ + t];
      s16x8 ax0{}, ax1{};
      if (use_x) {
        ax0 = cvt8(xs + ((size_t)rowg * T_ + t) * D_ + kg * 8);
        ax1 = cvt8(xs + ((size_t)rowg * T_ + t) * D_ + 32 + kg * 8);
      }

      f32x4 g0{}, g1{}, g2{}, i0{}, i1{}, i2{};

      if (t > 0) {
        if (wave == 0) {
          poll_step(cf, df, lane, (unsigned)t, (unsigned)(t - 1), budget);
          *mbx = t;
        } else {
          lds_wait(mbx, t);
        }
        // h loads at agent scope (coherence point) — no fence required
        const unsigned long long* hq = (const unsigned long long*)(hpv + arow);
        s16x8 a[16];
#pragma unroll
        for (int kc = 0; kc < 16; ++kc)
          a[kc] = ld_frag_agent(hq, kc * 8 + kg * 2);
        if (!use_x) {
#pragma unroll
          for (int kc = 0; kc < 16; ++kc) {
            g0 = mfma16(a[kc], whhf[0][kc], g0);
            g1 = mfma16(a[kc], whhf[1][kc], g1);
            g2 = mfma16(a[kc], whhf[2][kc], g2);
            i0 = mfma16(a[kc], fragK512(sm + OFF_WGI2, jl,      kc, kg), i0);
            i1 = mfma16(a[kc], fragK512(sm + OFF_WGI2, 16 + jl, kc, kg), i1);
            i2 = mfma16(a[kc], fragK512(sm + OFF_WGI2, 32 + jl, kc, kg), i2);
          }
        } else {
#pragma unroll
          for (int kc = 0; kc < 16; ++kc) {
            g0 = mfma16(a[kc], whhf[0][kc], g0);
            g1 = mfma16(a[kc], whhf[1][kc], g1);
            g2 = mfma16(a[kc], whhf[2][kc], g2);
          }
        }
      }
      if (use_x) {
        i0 = mfma16(ax0, fragK64(sm + OFF_WGIX, jl,      0, kg), i0);
        i1 = mfma16(ax0, fragK64(sm + OFF_WGIX, 16 + jl, 0, kg), i1);
        i2 = mfma16(ax0, fragK64(sm + OFF_WGIX, 32 + jl, 0, kg), i2);
        i0 = mfma16(ax1, fragK64(sm + OFF_WGIX, jl,      1, kg), i0);
        i1 = mfma16(ax1, fragK64(sm + OFF_WGIX, 16 + jl, 1, kg), i1);
        i2 = mfma16(ax1, fragK64(sm + OFF_WGIX, 32 + jl, 1, kg), i2);
      }

      // GRU in-register (all 6 gate tiles share (lane,reg) layout)
      unsigned short hb[4];
#pragma unroll
      for (int reg = 0; reg < 4; ++reg) {
        const float xr = i0[reg] + tsv[reg] * w0r + (use_x ? bir : c0r) + g0[reg] + bhr;
        const float xz = i1[reg] + tsv[reg] * w0z + (use_x ? biz : c0z) + g1[reg] + bhz;
        const float an = i2[reg] + tsv[reg] * w0n + (use_x ? bin_ : c0n);
        const float gn = g2[reg] + bhn;
        const float r = 1.f / (1.f + __expf(-xr));
        const float z = 1.f / (1.f + __expf(-xz));
        const float n = tanhf(an + r * gn);
        const float hn = (1.f - z) * n + z * hp[reg];
        hp[reg] = hn;
        hb[reg] = f2bf(hn);
      }
      // in-wave 16x16 transpose through LDS scratch -> one packed 8B store/lane
#pragma unroll
      for (int reg = 0; reg < 4; ++reg) scr[(kg * 4 + reg) * 16 + jl] = hb[reg];
      asm volatile("s_waitcnt lgkmcnt(0)" ::: "memory");
      __builtin_amdgcn_sched_barrier(0);
      {
        const int rr = lane & 15, q = lane >> 4;
        unsigned long long pk = *(const unsigned long long*)(scr + rr * 16 + q * 4);
        __hip_atomic_store(
            (unsigned long long*)(hcur + (size_t)(b0 + mt * 16 + rr) * H_ + j0) + q,
            pk, __ATOMIC_RELAXED, __HIP_MEMORY_SCOPE_AGENT);
      }
      asm volatile("s_waitcnt vmcnt(0)" ::: "memory");   // h at coherence point
      if (wave == 1) {
        if (lane == 0) *w1d = t + 1;
      } else if (lane == 0) {
        while (*w1d < t + 1) { __builtin_amdgcn_s_sleep(1); }
        __hip_atomic_store(myflag, (unsigned)(t + 1),
                           __ATOMIC_RELAXED, __HIP_MEMORY_SCOPE_AGENT);
      }
    }
    return;
  }

  // ============ decoder waves (2,3); only cg<8 participate ============
  if (cg >= 8) return;
  {
    s16x8 wd[16];
#pragma unroll
    for (int kc = 0; kc < 16; ++kc)
      wd[kc] = fragK512(sm + OFF_WDEC, jl, kc, kg);
    const float bd = ((const float*)(sm + OFF_BDECS))[jl];
    const int c = cg * 16 + jl;

    for (int v = 1; v < T_; ++v) {
      lds_wait(mbx, v);                                  // wave0 certified cflags>=v
      const unsigned short* hpv = hslab + (size_t)((v - 1) & 1) * (B_ * H_);
      const unsigned long long* hq = (const unsigned long long*)(hpv + arow);
      s16x8 a[16];
#pragma unroll
      for (int kc = 0; kc < 16; ++kc)
        a[kc] = ld_frag_agent(hq, kc * 8 + kg * 2);
      asm volatile("s_waitcnt vmcnt(0)" ::: "memory");   // reads done -> slab reusable
      if (wave == 3) {
        if (lane == 0) *d3d = v;
      } else if (lane == 0) {
        while (*d3d < v) { __builtin_amdgcn_s_sleep(1); }
        __hip_atomic_store(mydflag, (unsigned)v,
                           __ATOMIC_RELAXED, __HIP_MEMORY_SCOPE_AGENT);
      }
      f32x4 d{};
#pragma unroll
      for (int kc = 0; kc < 16; ++kc)
        d = mfma16(a[kc], wd[kc], d);
#pragma unroll
      for (int reg = 0; reg < 4; ++reg) {
        float vv = d[reg] + bd;
        if (c >= D_) vv = fmaxf(vv, 0.001f);
        out[((size_t)(hrow + reg) * T_ + (v - 1)) * O_ + c] = vv;
      }
    }

    // final step: h(T-1)
    if (wave == 2) {
      int bud2 = 10000000;
      poll_step(cf, cf, lane, (unsigned)T_, 0u, bud2);   // cflags only
      if (lane == 0) *mbx = T_;
    } else {
      lds_wait(mbx, T_);
    }
    const unsigned short* hpv = hslab + (size_t)((T_ - 1) & 1) * (B_ * H_);
    const unsigned long long* hq = (const unsigned long long*)(hpv + arow);
    s16x8 a[16];
#pragma unroll
    for (int kc = 0; kc < 16; ++kc)
      a[kc] = ld_frag_agent(hq, kc * 8 + kg * 2);
    f32x4 d{};
#pragma unroll
    for (int kc = 0; kc < 16; ++kc)
      d = mfma16(a[kc], wd[kc], d);
#pragma unroll
    for (int reg = 0; reg < 4; ++reg) {
      float vv = d[reg] + bd;
      if (c >= D_) vv = fmaxf(vv, 0.001f);
      out[((size_t)(hrow + reg) * T_ + (T_ - 1)) * O_ + c] = vv;
    }
  }
}

extern "C" void kernel_launch(void* const* d_in, const int* in_sizes, int n_in,
                              void* d_out, int out_size, void* d_ws, size_t ws_size,
                              hipStream_t stream) {
  const float* xs    = (const float*)d_in[0];
  const float* ts    = (const float*)d_in[1];
  const float* W_ih  = (const float*)d_in[2];
  const float* W_hh  = (const float*)d_in[3];
  const float* b_ih  = (const float*)d_in[4];
  const float* b_hh  = (const float*)d_in[5];
  const float* W_dec = (const float*)d_in[6];
  const float* b_dec = (const float*)d_in[7];
  const int* cutoff  = (const int*)d_in[8];
  float* out = (float*)d_out;

  char* ws = (char*)d_ws;
  unsigned short* Wcomb = (unsigned short*)(ws + WS_WCOMB);
  float* c0             = (float*)(ws + WS_C0);
  unsigned short* hslab = (unsigned short*)(ws + WS_HSLAB);
  unsigned* cflags      = (unsigned*)(ws + WS_CFLG);
  unsigned* dflags      = (unsigned*)(ws + WS_DFLG);

  hipMemsetAsync(ws + WS_CFLG, 0, WS_CTLSZ, stream);
  wcomb_kernel<<<1536, 256, 0, stream>>>(W_ih, W_dec, b_ih, b_dec, Wcomb, c0);
  hipFuncSetAttribute(reinterpret_cast<const void*>(rnn_persist),
                      hipFuncAttributeMaxDynamicSharedMemorySize, SMEM_BYTES);
  rnn_persist<<<256, 256, SMEM_BYTES, stream>>>(xs, ts, W_ih, W_hh, b_ih, b_hh,
                                                W_dec, b_dec, cutoff, Wcomb, c0,
                                                hslab, cflags, dflags, out);
}

// Round 8
// 6283.699 us; speedup vs baseline: 2.0732x; 1.1189x over previous
//
#include <hip/hip_runtime.h>
#include <hip/hip_bf16.h>
#include <cstdint>
#include <cstddef>

typedef float f32x4 __attribute__((ext_vector_type(4)));
typedef short s16x8 __attribute__((ext_vector_type(8)));

#define B_  256
#define T_  1024
#define D_  64
#define H_  512
#define O_  128
#define JW  16
#define NG  48

// ---- LDS layout (bytes) ----
#define OFF_WGH   0                 // [48][512] bf16 W_hh rows (swizzled)
#define OFF_WGI2  49152             // [48][512] bf16 W_comb rows
#define OFF_WGIX  98304             // [48][64]  bf16 W_ih x-part
#define OFF_WDEC  104448            // [16][512] bf16 W_dec slice (cg<8)
#define OFF_W0S   120832
#define OFF_C0S   121024
#define OFF_BIHS  121216
#define OFF_BHHS  121408
#define OFF_BDECS 121600
#define OFF_SCR   121728            // 2 waves * 16x16 u16 transpose scratch (1024B)
#define SMEM_BYTES 122752           // >80KB -> 1 WG/CU (co-residency guaranteed)

// ---- workspace layout (bytes) ----
#define WS_WCOMB 0                  // [1536][512] bf16
#define WS_C0    1572864            // [1536] f32
#define WS_HSLAB 1579008            // 2 * [256][512] bf16
#define WS_CFLG  2103296            // 8 rings * 64 uint = 2048 B
#define WS_CTLSZ 2048

__device__ inline f32x4 mfma16(s16x8 a, s16x8 b, f32x4 c) {
  return __builtin_amdgcn_mfma_f32_16x16x32_bf16(a, b, c, 0, 0, 0);
}

__device__ inline unsigned short f2bf(float f) {
  __hip_bfloat16 h = __float2bfloat16(f);
  unsigned short u;
  __builtin_memcpy(&u, &h, sizeof(u));
  return u;
}

__device__ inline s16x8 cvt8(const float* s) {
  union { unsigned short h[8]; s16x8 v; } p;
#pragma unroll
  for (int e = 0; e < 8; ++e) p.h[e] = f2bf(s[e]);
  return p.v;
}

// B-fragment readers (rows K-contiguous, 16B-block XOR swizzle by (row&7)<<4)
__device__ inline s16x8 fragK512(const char* base, int n, int kc, int kg) {
  int byteoff = n * 1024 + (((kc * 64) + (kg * 16)) ^ ((n & 7) << 4));
  return *(const s16x8*)(base + byteoff);
}
__device__ inline s16x8 fragK64(const char* base, int n, int kc, int kg) {
  int byteoff = n * 128 + (((kc * 64) + (kg * 16)) ^ ((n & 7) << 4));
  return *(const s16x8*)(base + byteoff);
}

// coherent-point (agent) load of one 16B MFMA A-fragment as 2x u64 atomic loads
__device__ inline s16x8 ld_frag_agent(const unsigned long long* hq, int idx) {
  union { unsigned long long q[2]; s16x8 v; } u;
  u.q[0] = __hip_atomic_load(hq + idx,     __ATOMIC_RELAXED, __HIP_MEMORY_SCOPE_AGENT);
  u.q[1] = __hip_atomic_load(hq + idx + 1, __ATOMIC_RELAXED, __HIP_MEMORY_SCOPE_AGENT);
  return u.v;
}

// all 64 lanes poll one ring slot each (64 slots = 32 WGs x 2 waves)
__device__ inline void poll64(const unsigned* ring, int lane, unsigned tgt, int& budget) {
  const unsigned* a = ring + lane;
  for (;;) {
    unsigned v = __hip_atomic_load(a, __ATOMIC_RELAXED, __HIP_MEMORY_SCOPE_AGENT);
    if (__all((int)(v >= tgt))) break;
    if (--budget <= 0) break;
    __builtin_amdgcn_s_sleep(1);
  }
  asm volatile("" ::: "memory");
}

// ---------------- W_comb = W_ih[:,1:65] @ W_dec[:64,:]  (+ c0) ----------------
__global__ void wcomb_kernel(const float* __restrict__ W_ih, const float* __restrict__ W_dec,
                             const float* __restrict__ b_ih, const float* __restrict__ b_dec,
                             unsigned short* __restrict__ Wcomb, float* __restrict__ c0) {
  __shared__ float arow[64];
  int i = blockIdx.x;
  int tid = threadIdx.x;
  if (tid < 64) arow[tid] = W_ih[(size_t)i * 65 + 1 + tid];
  __syncthreads();
  for (int j = tid; j < H_; j += 256) {
    float acc = 0.f;
#pragma unroll 8
    for (int d = 0; d < 64; ++d) acc += arow[d] * W_dec[(size_t)d * H_ + j];
    Wcomb[(size_t)i * H_ + j] = f2bf(acc);
  }
  if (tid == 0) {
    float acc = b_ih[i];
    for (int d = 0; d < 64; ++d) acc += arow[d] * b_dec[d];
    c0[i] = acc;
  }
}

// ---------------- persistent recurrence: 2 waves/WG, decode fused ----------------
__global__ __launch_bounds__(128, 1) void rnn_persist(
    const float* __restrict__ xs, const float* __restrict__ ts,
    const float* __restrict__ W_ih, const float* __restrict__ W_hh,
    const float* __restrict__ b_ih, const float* __restrict__ b_hh,
    const float* __restrict__ W_dec, const float* __restrict__ b_dec,
    const int* __restrict__ cutoffp,
    const unsigned short* __restrict__ Wcomb, const float* __restrict__ c0,
    unsigned short* __restrict__ hslab, unsigned* __restrict__ cflags,
    float* __restrict__ out) {
  extern __shared__ char sm[];
  const int tid = threadIdx.x;
  const int wave = tid >> 6, lane = tid & 63;
  const int jl = lane & 15, kg = lane >> 4;
  const int cutoff = *cutoffp;

  const int bg = blockIdx.x & 7;
  const int cg = blockIdx.x >> 3;
  const int b0 = bg * 32;
  const int j0 = cg * JW;

  // ---- one-time LDS fill (weights, swizzled; R2-proven layout) ----
  for (int u = tid; u < NG * 64; u += 128) {
    int r = u >> 6, blk = u & 63;
    int grow = (r >> 4) * H_ + j0 + (r & 15);
    s16x8 v = cvt8(W_hh + (size_t)grow * H_ + blk * 8);
    *(s16x8*)(sm + OFF_WGH + r * 1024 + ((blk * 16) ^ ((r & 7) << 4))) = v;
  }
  for (int u = tid; u < NG * 64; u += 128) {
    int r = u >> 6, blk = u & 63;
    int grow = (r >> 4) * H_ + j0 + (r & 15);
    s16x8 v = *(const s16x8*)(Wcomb + (size_t)grow * H_ + blk * 8);
    *(s16x8*)(sm + OFF_WGI2 + r * 1024 + ((blk * 16) ^ ((r & 7) << 4))) = v;
  }
  for (int u = tid; u < NG * 8; u += 128) {
    int r = u >> 3, blk = u & 7;
    int grow = (r >> 4) * H_ + j0 + (r & 15);
    s16x8 v = cvt8(W_ih + (size_t)grow * 65 + 1 + blk * 8);
    *(s16x8*)(sm + OFF_WGIX + r * 128 + ((blk * 16) ^ ((r & 7) << 4))) = v;
  }
  if (cg < 8) {
    for (int u = tid; u < 16 * 64; u += 128) {
      int r = u >> 6, blk = u & 63;
      s16x8 v = cvt8(W_dec + (size_t)(cg * 16 + r) * H_ + blk * 8);
      *(s16x8*)(sm + OFF_WDEC + r * 1024 + ((blk * 16) ^ ((r & 7) << 4))) = v;
    }
    if (tid < 16) ((float*)(sm + OFF_BDECS))[tid] = b_dec[cg * 16 + tid];
  }
  if (tid < NG) {
    int grow = (tid >> 4) * H_ + j0 + (tid & 15);
    ((float*)(sm + OFF_W0S))[tid]  = W_ih[(size_t)grow * 65];
    ((float*)(sm + OFF_C0S))[tid]  = c0[grow];
    ((float*)(sm + OFF_BIHS))[tid] = b_ih[grow];
    ((float*)(sm + OFF_BHHS))[tid] = b_hh[grow];
  }
  __syncthreads();

  const int mt = wave;                          // M-tile: 16 rows per wave
  const int rowg = b0 + mt * 16 + jl;           // A-frag row
  const size_t arow = (size_t)rowg * H_;
  const int hrow = b0 + mt * 16 + kg * 4;       // C-tile row base
  const unsigned* ring = cflags + bg * 64;
  unsigned* myflag = cflags + bg * 64 + cg * 2 + mt;
  unsigned short* scr = (unsigned short*)(sm + OFF_SCR) + mt * 256;
  int budget = 10000000;

  const float* W0S  = (const float*)(sm + OFF_W0S);
  const float* C0S  = (const float*)(sm + OFF_C0S);
  const float* BIHS = (const float*)(sm + OFF_BIHS);
  const float* BHHS = (const float*)(sm + OFF_BHHS);
  const float w0r = W0S[jl],  w0z = W0S[16 + jl],  w0n = W0S[32 + jl];
  const float bir = BIHS[jl], biz = BIHS[16 + jl], bin_ = BIHS[32 + jl];
  const float c0r = C0S[jl],  c0z = C0S[16 + jl],  c0n = C0S[32 + jl];
  const float bhr = BHHS[jl], bhz = BHHS[16 + jl], bhn = BHHS[32 + jl];

  s16x8 whhf[3][16];
#pragma unroll
  for (int g = 0; g < 3; ++g)
#pragma unroll
    for (int kc = 0; kc < 16; ++kc)
      whhf[g][kc] = fragK512(sm + OFF_WGH, g * 16 + jl, kc, kg);

  const bool do_dec = (cg < 8);
  const float bd = do_dec ? ((const float*)(sm + OFF_BDECS))[jl] : 0.f;
  const int oc = cg * 16 + jl;                  // decode out-col

  float hp[4] = {0.f, 0.f, 0.f, 0.f};

  for (int t = 0; t < T_; ++t) {
    const bool use_x = (t < cutoff) || (t == 0);
    unsigned short* hcur = hslab + (size_t)(t & 1) * (B_ * H_);
    const unsigned short* hpv = hslab + (size_t)((t + 1) & 1) * (B_ * H_);

    // prefetch (no h dependency)
    float tsv[4];
#pragma unroll
    for (int reg = 0; reg < 4; ++reg) tsv[reg] = ts[(size_t)(hrow + reg) * T_ + t];

    f32x4 g0{}, g1{}, g2{}, i0{}, i1{}, i2{};
    if (use_x) {                                 // xs-side gi: fully pre-poll
      s16x8 ax0 = cvt8(xs + ((size_t)rowg * T_ + t) * D_ + kg * 8);
      s16x8 ax1 = cvt8(xs + ((size_t)rowg * T_ + t) * D_ + 32 + kg * 8);
      i0 = mfma16(ax0, fragK64(sm + OFF_WGIX, jl,      0, kg), i0);
      i1 = mfma16(ax0, fragK64(sm + OFF_WGIX, 16 + jl, 0, kg), i1);
      i2 = mfma16(ax0, fragK64(sm + OFF_WGIX, 32 + jl, 0, kg), i2);
      i0 = mfma16(ax1, fragK64(sm + OFF_WGIX, jl,      1, kg), i0);
      i1 = mfma16(ax1, fragK64(sm + OFF_WGIX, 16 + jl, 1, kg), i1);
      i2 = mfma16(ax1, fragK64(sm + OFF_WGIX, 32 + jl, 1, kg), i2);
    }

    s16x8 a[16];
    if (t > 0) {
      poll64(ring, lane, (unsigned)t, budget);   // peers wrote h(t-1); slab t&1 free
      const unsigned long long* hq = (const unsigned long long*)(hpv + arow);
#pragma unroll
      for (int kc = 0; kc < 16; ++kc)
        a[kc] = ld_frag_agent(hq, kc * 8 + kg * 2);
      if (!use_x) {
#pragma unroll
        for (int kc = 0; kc < 16; ++kc) {
          g0 = mfma16(a[kc], whhf[0][kc], g0);
          g1 = mfma16(a[kc], whhf[1][kc], g1);
          g2 = mfma16(a[kc], whhf[2][kc], g2);
          i0 = mfma16(a[kc], fragK512(sm + OFF_WGI2, jl,      kc, kg), i0);
          i1 = mfma16(a[kc], fragK512(sm + OFF_WGI2, 16 + jl, kc, kg), i1);
          i2 = mfma16(a[kc], fragK512(sm + OFF_WGI2, 32 + jl, kc, kg), i2);
        }
      } else {
#pragma unroll
        for (int kc = 0; kc < 16; ++kc) {
          g0 = mfma16(a[kc], whhf[0][kc], g0);
          g1 = mfma16(a[kc], whhf[1][kc], g1);
          g2 = mfma16(a[kc], whhf[2][kc], g2);
        }
      }
    }

    // GRU in-register (all 6 gate tiles share (lane,reg) layout)
    unsigned short hb[4];
#pragma unroll
    for (int reg = 0; reg < 4; ++reg) {
      const float xr = i0[reg] + tsv[reg] * w0r + (use_x ? bir : c0r) + g0[reg] + bhr;
      const float xz = i1[reg] + tsv[reg] * w0z + (use_x ? biz : c0z) + g1[reg] + bhz;
      const float an = i2[reg] + tsv[reg] * w0n + (use_x ? bin_ : c0n);
      const float gn = g2[reg] + bhn;
      const float r = 1.f / (1.f + __expf(-xr));
      const float z = 1.f / (1.f + __expf(-xz));
      const float n = tanhf(an + r * gn);
      const float hn = (1.f - z) * n + z * hp[reg];
      hp[reg] = hn;
      hb[reg] = f2bf(hn);
    }
    // in-wave 16x16 transpose through LDS scratch -> one packed 8B store/lane
#pragma unroll
    for (int reg = 0; reg < 4; ++reg) scr[(kg * 4 + reg) * 16 + jl] = hb[reg];
    asm volatile("s_waitcnt lgkmcnt(0)" ::: "memory");
    __builtin_amdgcn_sched_barrier(0);
    {
      const int rr = lane & 15, q = lane >> 4;
      unsigned long long pk = *(const unsigned long long*)(scr + rr * 16 + q * 4);
      __hip_atomic_store(
          (unsigned long long*)(hcur + (size_t)(b0 + mt * 16 + rr) * H_ + j0) + q,
          pk, __ATOMIC_RELAXED, __HIP_MEMORY_SCOPE_AGENT);
    }
    asm volatile("s_waitcnt vmcnt(0)" ::: "memory");     // h at coherence point
    if (lane == 0)
      __hip_atomic_store(myflag, (unsigned)(t + 1),
                         __ATOMIC_RELAXED, __HIP_MEMORY_SCOPE_AGENT);

    // off-chain: decode step t-1 from registers (a[] = h(t-1))
    if (do_dec && t > 0) {
      f32x4 dacc{};
#pragma unroll
      for (int kc = 0; kc < 16; ++kc)
        dacc = mfma16(a[kc], fragK512(sm + OFF_WDEC, jl, kc, kg), dacc);
#pragma unroll
      for (int reg = 0; reg < 4; ++reg) {
        float vv = dacc[reg] + bd;
        if (oc >= D_) vv = fmaxf(vv, 0.001f);
        out[((size_t)(hrow + reg) * T_ + (t - 1)) * O_ + oc] = vv;
      }
    }
  }

  // epilogue: decode final step h(T-1)
  if (do_dec) {
    poll64(ring, lane, (unsigned)T_, budget);
    const unsigned short* hpv = hslab + (size_t)((T_ - 1) & 1) * (B_ * H_);
    const unsigned long long* hq = (const unsigned long long*)(hpv + arow);
    s16x8 a[16];
#pragma unroll
    for (int kc = 0; kc < 16; ++kc)
      a[kc] = ld_frag_agent(hq, kc * 8 + kg * 2);
    f32x4 dacc{};
#pragma unroll
    for (int kc = 0; kc < 16; ++kc)
      dacc = mfma16(a[kc], fragK512(sm + OFF_WDEC, jl, kc, kg), dacc);
#pragma unroll
    for (int reg = 0; reg < 4; ++reg) {
      float vv = dacc[reg] + bd;
      if (oc >= D_) vv = fmaxf(vv, 0.001f);
      out[((size_t)(hrow + reg) * T_ + (T_ - 1)) * O_ + oc] = vv;
    }
  }
}

extern "C" void kernel_launch(void* const* d_in, const int* in_sizes, int n_in,
                              void* d_out, int out_size, void* d_ws, size_t ws_size,
                              hipStream_t stream) {
  const float* xs    = (const float*)d_in[0];
  const float* ts    = (const float*)d_in[1];
  const float* W_ih  = (const float*)d_in[2];
  const float* W_hh  = (const float*)d_in[3];
  const float* b_ih  = (const float*)d_in[4];
  const float* b_hh  = (const float*)d_in[5];
  const float* W_dec = (const float*)d_in[6];
  const float* b_dec = (const float*)d_in[7];
  const int* cutoff  = (const int*)d_in[8];
  float* out = (float*)d_out;

  char* ws = (char*)d_ws;
  unsigned short* Wcomb = (unsigned short*)(ws + WS_WCOMB);
  float* c0             = (float*)(ws + WS_C0);
  unsigned short* hslab = (unsigned short*)(ws + WS_HSLAB);
  unsigned* cflags      = (unsigned*)(ws + WS_CFLG);

  hipMemsetAsync(ws + WS_CFLG, 0, WS_CTLSZ, stream);
  wcomb_kernel<<<1536, 256, 0, stream>>>(W_ih, W_dec, b_ih, b_dec, Wcomb, c0);
  hipFuncSetAttribute(reinterpret_cast<const void*>(rnn_persist),
                      hipFuncAttributeMaxDynamicSharedMemorySize, SMEM_BYTES);
  rnn_persist<<<256, 128, SMEM_BYTES, stream>>>(xs, ts, W_ih, W_hh, b_ih, b_hh,
                                                W_dec, b_dec, cutoff, Wcomb, c0,
                                                hslab, cflags, out);
}